// Round 5
// baseline (240.585 us; speedup 1.0000x reference)
//
#include <hip/hip_runtime.h>
#include <math.h>

#define BB 8
#define NN 512
#define FF 128
#define TT 32
#define DD 64
constexpr float EPS = 1e-6f;

typedef _Float16 half8 __attribute__((ext_vector_type(8)));
typedef _Float16 half4v __attribute__((ext_vector_type(4)));
typedef float f32x4 __attribute__((ext_vector_type(4)));

__device__ __forceinline__ float fast_tanh(float v) {
    float e = __expf(2.f * v);
    return 1.f - 2.f * __builtin_amdgcn_rcpf(e + 1.f);
}

// ---------------- Stage 1: z = tanh(x @ W^T + b) -> fp16 hi/lo split, d-major layout ----------------
// z layout: [b][t][n][d] row-major (one n-row = 128 B = one cache line per buffer)
// grid: B * (N/2) = 2048 blocks, 256 threads
__global__ __launch_bounds__(256) void z_kernel(const float* __restrict__ x,
                                                const float* __restrict__ W,
                                                const float* __restrict__ bias,
                                                _Float16* __restrict__ zh,
                                                _Float16* __restrict__ zl,
                                                float* __restrict__ sqv,
                                                float* __restrict__ nvv) {
    extern __shared__ float lds[];
    float* xs = lds;                      // 2*32*132 floats
    float* Wt = lds + 2 * 32 * 132;       // 128*64 floats
    const int tid = threadIdx.x;
    const int b  = blockIdx.x >> 8;
    const int n0 = (blockIdx.x & 255) * 2;

    const float4* W4 = (const float4*)W;
    #pragma unroll
    for (int it = 0; it < 8; ++it) {
        int idx4 = tid + it * 256;
        float4 w = W4[idx4];
        int d = idx4 >> 5;
        int f = (idx4 & 31) * 4;
        Wt[(f + 0) * 64 + d] = w.x;
        Wt[(f + 1) * 64 + d] = w.y;
        Wt[(f + 2) * 64 + d] = w.z;
        Wt[(f + 3) * 64 + d] = w.w;
    }
    const float4* x4 = (const float4*)(x + ((size_t)b * NN + n0) * FF * TT);
    #pragma unroll
    for (int it = 0; it < 8; ++it) {
        int idx4 = tid + it * 256;
        float4 v = x4[idx4];
        int e   = idx4 * 4;
        int ns  = e >> 12;
        int rem = e & 4095;
        int f   = rem >> 5;
        int t   = rem & 31;
        float* base = xs + ns * (32 * 132) + t * 132 + f;
        base[0 * 132] = v.x;
        base[1 * 132] = v.y;
        base[2 * 132] = v.z;
        base[3 * 132] = v.w;
    }
    __syncthreads();

    const int t  = tid >> 3;
    const int dg = tid & 7;
    const int d0 = dg * 8;
    float acc[2][8];
    #pragma unroll
    for (int ns = 0; ns < 2; ++ns)
        #pragma unroll
        for (int dd = 0; dd < 8; ++dd) acc[ns][dd] = 0.f;

    #pragma unroll 4
    for (int fc = 0; fc < FF; fc += 4) {
        float wv[4][8];
        #pragma unroll
        for (int k = 0; k < 4; ++k) {
            float4 a = *(const float4*)&Wt[(fc + k) * 64 + d0];
            float4 c = *(const float4*)&Wt[(fc + k) * 64 + d0 + 4];
            wv[k][0] = a.x; wv[k][1] = a.y; wv[k][2] = a.z; wv[k][3] = a.w;
            wv[k][4] = c.x; wv[k][5] = c.y; wv[k][6] = c.z; wv[k][7] = c.w;
        }
        #pragma unroll
        for (int ns = 0; ns < 2; ++ns) {
            float4 xv = *(const float4*)&xs[ns * (32 * 132) + t * 132 + fc];
            float xk[4] = {xv.x, xv.y, xv.z, xv.w};
            #pragma unroll
            for (int dd = 0; dd < 8; ++dd) {
                acc[ns][dd] += xk[0] * wv[0][dd] + xk[1] * wv[1][dd]
                             + xk[2] * wv[2][dd] + xk[3] * wv[3][dd];
            }
        }
    }

    float bb[8];
    #pragma unroll
    for (int dd = 0; dd < 8; ++dd) bb[dd] = bias[d0 + dd];

    const size_t rowbase = ((size_t)b * TT + t) * NN + n0;
    float sqp[2];
    #pragma unroll
    for (int ns = 0; ns < 2; ++ns) {
        half8 hv, lv;
        float sp = 0.f;
        #pragma unroll
        for (int dd = 0; dd < 8; ++dd) {
            float zf = fast_tanh(acc[ns][dd] + bb[dd]);
            sp += zf * zf;
            _Float16 h = (_Float16)zf;
            hv[dd] = h;
            lv[dd] = (_Float16)(zf - (float)h);
        }
        size_t off = (rowbase + ns) * DD + d0;   // d-major: full 128-B lines per (t,n)
        *(half8*)(zh + off) = hv;
        *(half8*)(zl + off) = lv;
        sqp[ns] = sp;
    }
    #pragma unroll
    for (int k = 1; k < 8; k <<= 1) {
        #pragma unroll
        for (int ns = 0; ns < 2; ++ns) sqp[ns] += __shfl_xor(sqp[ns], k);
    }
    if (dg == 0) {
        #pragma unroll
        for (int ns = 0; ns < 2; ++ns) {
            sqv[rowbase + ns] = sqp[ns];
            nvv[rowbase + ns] = sqrtf(sqp[ns]) + EPS;
        }
    }
}

// ---------------- Stage 2: S = Z Z^T via split-fp16 MFMA ----------------
// grid: 1024 blocks (t = bid&31, rowtile16 = bid>>5), 256 threads = 4 waves.
// wave w: rows n0..n0+15, cols w*128..w*128+127 (8 col-tiles), depth-1 B prefetch.
__global__ __launch_bounds__(256, 4) void att5_kernel(const _Float16* __restrict__ zh,
                                                      const _Float16* __restrict__ zl,
                                                      const float* __restrict__ sqv,
                                                      const float* __restrict__ nvv,
                                                      float* __restrict__ out) {
    // union: os[16][516] fp32 (33024 B) overlaps {nv_s[2][512] | sq_s[2][512] | rs_s[2][4][16]}
    __shared__ __align__(16) char smem[16 * 516 * 4];
    float* os   = (float*)smem;
    float* nv_s = (float*)smem;              // [2][512]
    float* sq_s = nv_s + 1024;               // [2][512]
    float* rs_s = sq_s + 1024;               // [2][4][16]

    const int tid  = threadIdx.x;
    const int w    = tid >> 6;
    const int lane = tid & 63;
    const int l15  = lane & 15;
    const int g    = lane >> 4;
    const int t    = blockIdx.x & 31;
    const int n0   = (blockIdx.x >> 5) * 16;

    float acc[8][4];
    #pragma unroll
    for (int ct = 0; ct < 8; ++ct)
        #pragma unroll
        for (int ri = 0; ri < 4; ++ri) acc[ct][ri] = 0.f;

    half4v atth[8];

    for (int b = 0; b < BB; ++b) {
        const int p = b & 1;
        const size_t nbase = ((size_t)b * TT + t) * NN;
        const size_t slab  = nbase * DD;
        nv_s[p * NN + tid]       = nvv[nbase + tid];
        nv_s[p * NN + tid + 256] = nvv[nbase + tid + 256];
        sq_s[p * NN + tid]       = sqv[nbase + tid];
        sq_s[p * NN + tid + 256] = sqv[nbase + tid + 256];

        const _Float16* zhp = zh + slab;
        const _Float16* zlp = zl + slab;

        // A fragments: rows n0+l15, k = s*32 + g*8 + i
        half8 ah[2], al[2];
        #pragma unroll
        for (int s = 0; s < 2; ++s) {
            const size_t ro = (size_t)(n0 + l15) * DD + s * 32 + g * 8;
            ah[s] = *(const half8*)(zhp + ro);
            al[s] = *(const half8*)(zlp + ro);
        }
        __syncthreads();

        float nr[4], sq_r[4], nri[4];
        #pragma unroll
        for (int ri = 0; ri < 4; ++ri) {
            int row = n0 + g * 4 + ri;
            nr[ri]   = nv_s[p * NN + row];
            sq_r[ri] = sq_s[p * NN + row];
            nri[ri]  = __builtin_amdgcn_rcpf(nr[ri]);
        }

        float rs[4] = {0.f, 0.f, 0.f, 0.f};

        // depth-1 prefetch over 8 col-tiles
        half8 bh0c, bh1c, bl0c, bl1c;
        {
            const size_t co = (size_t)(w * 128 + l15) * DD + g * 8;
            bh0c = *(const half8*)(zhp + co);
            bh1c = *(const half8*)(zhp + co + 32);
            bl0c = *(const half8*)(zlp + co);
            bl1c = *(const half8*)(zlp + co + 32);
        }
        #pragma unroll
        for (int ct = 0; ct < 8; ++ct) {
            half8 bh0n, bh1n, bl0n, bl1n;
            if (ct < 7) {
                const size_t co = (size_t)(w * 128 + (ct + 1) * 16 + l15) * DD + g * 8;
                bh0n = *(const half8*)(zhp + co);
                bh1n = *(const half8*)(zhp + co + 32);
                bl0n = *(const half8*)(zlp + co);
                bl1n = *(const half8*)(zlp + co + 32);
            }
            // 3 independent 2-deep MFMA chains
            f32x4 dhh = {0.f, 0.f, 0.f, 0.f};
            f32x4 dhl = {0.f, 0.f, 0.f, 0.f};
            f32x4 dlh = {0.f, 0.f, 0.f, 0.f};
            dhh = __builtin_amdgcn_mfma_f32_16x16x32_f16(ah[0], bh0c, dhh, 0, 0, 0);
            dhl = __builtin_amdgcn_mfma_f32_16x16x32_f16(ah[0], bl0c, dhl, 0, 0, 0);
            dlh = __builtin_amdgcn_mfma_f32_16x16x32_f16(al[0], bh0c, dlh, 0, 0, 0);
            dhh = __builtin_amdgcn_mfma_f32_16x16x32_f16(ah[1], bh1c, dhh, 0, 0, 0);
            dhl = __builtin_amdgcn_mfma_f32_16x16x32_f16(ah[1], bl1c, dhl, 0, 0, 0);
            dlh = __builtin_amdgcn_mfma_f32_16x16x32_f16(al[1], bh1c, dlh, 0, 0, 0);
            f32x4 d = dhh + dhl + dlh;

            const int col   = w * 128 + ct * 16 + l15;
            const float nm  = nv_s[p * NN + col];
            const float sqm = sq_s[p * NN + col];
            const float nmi = __builtin_amdgcn_rcpf(nm);
            float pr[4], s2[4], rc[4];
            #pragma unroll
            for (int ri = 0; ri < 4; ++ri) {
                pr[ri] = nri[ri] * nmi;
                s2[ri] = sq_r[ri] + sqm;
                rc[ri] = __builtin_amdgcn_rcpf(nr[ri] + nm + EPS);
            }
            #pragma unroll
            for (int ri = 0; ri < 4; ++ri) {
                float dot = d[ri];
                float cs  = dot * pr[ri];
                float d2  = fmaxf(fmaf(dot, -2.f, s2[ri]), 0.f);
                float dn  = __builtin_amdgcn_sqrtf(d2);
                float a   = __expf(fmaf(dn, -rc[ri], cs));
                atth[ct][ri] = (_Float16)a;
                rs[ri] += a;
            }
            bh0c = bh0n; bh1c = bh1n; bl0c = bl0n; bl1c = bl1n;
        }

        // row-sum across the 16 lanes of each g-group
        #pragma unroll
        for (int ri = 0; ri < 4; ++ri) {
            float v = rs[ri];
            v += __shfl_xor(v, 1);
            v += __shfl_xor(v, 2);
            v += __shfl_xor(v, 4);
            v += __shfl_xor(v, 8);
            rs[ri] = v;
        }
        if (l15 == 0) {
            #pragma unroll
            for (int ri = 0; ri < 4; ++ri)
                rs_s[(p * 4 + w) * 16 + g * 4 + ri] = rs[ri];
        }
        __syncthreads();
        #pragma unroll
        for (int ri = 0; ri < 4; ++ri) {
            int rl = g * 4 + ri;
            float tot = rs_s[(p * 4 + 0) * 16 + rl] + rs_s[(p * 4 + 1) * 16 + rl]
                      + rs_s[(p * 4 + 2) * 16 + rl] + rs_s[(p * 4 + 3) * 16 + rl];
            float rinv = __builtin_amdgcn_rcpf(tot + EPS);
            #pragma unroll
            for (int ct = 0; ct < 8; ++ct)
                acc[ct][ri] += (float)atth[ct][ri] * rinv;
        }
    }

    // transpose through LDS for fully-coalesced out writes
    __syncthreads();
    #pragma unroll
    for (int ri = 0; ri < 4; ++ri)
        #pragma unroll
        for (int ct = 0; ct < 8; ++ct)
            os[(g * 4 + ri) * 516 + w * 128 + ct * 16 + l15] = acc[ct][ri] * 0.125f;
    __syncthreads();
    #pragma unroll
    for (int it = 0; it < 8; ++it) {
        int idx4 = tid + it * 256;          // 2048 float4
        int row  = idx4 >> 7;
        int c    = (idx4 & 127) * 4;
        float4 v = *(const float4*)&os[row * 516 + c];
        *(float4*)(out + ((size_t)t * NN + n0 + row) * NN + c) = v;
    }
}

extern "C" void kernel_launch(void* const* d_in, const int* in_sizes, int n_in,
                              void* d_out, int out_size, void* d_ws, size_t ws_size,
                              hipStream_t stream) {
    const float* x    = (const float*)d_in[0];
    const float* W    = (const float*)d_in[1];
    const float* bias = (const float*)d_in[2];
    float* out = (float*)d_out;

    const size_t ZELEMS = (size_t)BB * TT * NN * DD;
    _Float16* zh = (_Float16*)d_ws;
    _Float16* zl = zh + ZELEMS;
    float* sqv = (float*)(zh + 2 * ZELEMS);
    float* nvv = sqv + (size_t)BB * TT * NN;

    z_kernel<<<dim3(BB * (NN / 2)), dim3(256), 66560, stream>>>(x, W, bias, zh, zl, sqv, nvv);
    att5_kernel<<<dim3(TT * (NN / 16)), dim3(256), 0, stream>>>(zh, zl, sqv, nvv, out);
}

// Round 7
// 151.826 us; speedup vs baseline: 1.5846x; 1.5846x over previous
//
#include <hip/hip_runtime.h>
#include <math.h>

#define BB 8
#define NN 512
#define FF 128
#define TT 32
#define DD 64
constexpr float EPS = 1e-6f;

typedef _Float16 half8 __attribute__((ext_vector_type(8)));
typedef _Float16 half4v __attribute__((ext_vector_type(4)));
typedef float f32x4 __attribute__((ext_vector_type(4)));

extern __shared__ char dynsmem[];

__device__ __forceinline__ float fast_tanh(float v) {
    float e = __expf(2.f * v);
    return 1.f - 2.f * __builtin_amdgcn_rcpf(e + 1.f);
}

__device__ __forceinline__ void gl_lds16(const void* g, void* l) {
    __builtin_amdgcn_global_load_lds((const __attribute__((address_space(1))) unsigned int*)g,
                                     (__attribute__((address_space(3))) unsigned int*)l,
                                     16, 0, 0);
}

// ---------------- Stage 1: z = tanh(x @ W^T + b) -> fp16 hi/lo split, swizzled d-major ----------------
// z layout: [b][t][n][octet ^ (n&7)][8]  (128-B row per (t,n); octets XOR-permuted so a linear
// global->LDS copy yields a bank-conflict-free LDS image for column reads)
// grid: B * (N/2) = 2048 blocks, 256 threads
__global__ __launch_bounds__(256) void z_kernel(const float* __restrict__ x,
                                                const float* __restrict__ W,
                                                const float* __restrict__ bias,
                                                _Float16* __restrict__ zh,
                                                _Float16* __restrict__ zl,
                                                float* __restrict__ sqv,
                                                float* __restrict__ nvv) {
    float* lds = (float*)dynsmem;
    float* xs = lds;                      // 2*32*132 floats
    float* Wt = lds + 2 * 32 * 132;       // 128*64 floats
    const int tid = threadIdx.x;
    const int b  = blockIdx.x >> 8;
    const int n0 = (blockIdx.x & 255) * 2;

    const float4* W4 = (const float4*)W;
    #pragma unroll
    for (int it = 0; it < 8; ++it) {
        int idx4 = tid + it * 256;
        float4 w = W4[idx4];
        int d = idx4 >> 5;
        int f = (idx4 & 31) * 4;
        Wt[(f + 0) * 64 + d] = w.x;
        Wt[(f + 1) * 64 + d] = w.y;
        Wt[(f + 2) * 64 + d] = w.z;
        Wt[(f + 3) * 64 + d] = w.w;
    }
    const float4* x4 = (const float4*)(x + ((size_t)b * NN + n0) * FF * TT);
    #pragma unroll
    for (int it = 0; it < 8; ++it) {
        int idx4 = tid + it * 256;
        float4 v = x4[idx4];
        int e   = idx4 * 4;
        int ns  = e >> 12;
        int rem = e & 4095;
        int f   = rem >> 5;
        int t   = rem & 31;
        float* base = xs + ns * (32 * 132) + t * 132 + f;
        base[0 * 132] = v.x;
        base[1 * 132] = v.y;
        base[2 * 132] = v.z;
        base[3 * 132] = v.w;
    }
    __syncthreads();

    const int t  = tid >> 3;
    const int dg = tid & 7;
    const int d0 = dg * 8;
    float acc[2][8];
    #pragma unroll
    for (int ns = 0; ns < 2; ++ns)
        #pragma unroll
        for (int dd = 0; dd < 8; ++dd) acc[ns][dd] = 0.f;

    #pragma unroll 4
    for (int fc = 0; fc < FF; fc += 4) {
        float wv[4][8];
        #pragma unroll
        for (int k = 0; k < 4; ++k) {
            float4 a = *(const float4*)&Wt[(fc + k) * 64 + d0];
            float4 c = *(const float4*)&Wt[(fc + k) * 64 + d0 + 4];
            wv[k][0] = a.x; wv[k][1] = a.y; wv[k][2] = a.z; wv[k][3] = a.w;
            wv[k][4] = c.x; wv[k][5] = c.y; wv[k][6] = c.z; wv[k][7] = c.w;
        }
        #pragma unroll
        for (int ns = 0; ns < 2; ++ns) {
            float4 xv = *(const float4*)&xs[ns * (32 * 132) + t * 132 + fc];
            float xk[4] = {xv.x, xv.y, xv.z, xv.w};
            #pragma unroll
            for (int dd = 0; dd < 8; ++dd) {
                acc[ns][dd] += xk[0] * wv[0][dd] + xk[1] * wv[1][dd]
                             + xk[2] * wv[2][dd] + xk[3] * wv[3][dd];
            }
        }
    }

    float bb[8];
    #pragma unroll
    for (int dd = 0; dd < 8; ++dd) bb[dd] = bias[d0 + dd];

    const size_t rowbase = ((size_t)b * TT + t) * NN + n0;
    float sqp[2];
    #pragma unroll
    for (int ns = 0; ns < 2; ++ns) {
        half8 hv, lv;
        float sp = 0.f;
        #pragma unroll
        for (int dd = 0; dd < 8; ++dd) {
            float zf = fast_tanh(acc[ns][dd] + bb[dd]);
            sp += zf * zf;
            _Float16 h = (_Float16)zf;
            hv[dd] = h;
            lv[dd] = (_Float16)(zf - (float)h);
        }
        // swizzled octet position within the 128-B row
        size_t off = (rowbase + ns) * DD + (size_t)((dg ^ ((n0 + ns) & 7)) * 8);
        *(half8*)(zh + off) = hv;
        *(half8*)(zl + off) = lv;
        sqp[ns] = sp;
    }
    #pragma unroll
    for (int k = 1; k < 8; k <<= 1) {
        #pragma unroll
        for (int ns = 0; ns < 2; ++ns) sqp[ns] += __shfl_xor(sqp[ns], k);
    }
    if (dg == 0) {
        #pragma unroll
        for (int ns = 0; ns < 2; ++ns) {
            sqv[rowbase + ns] = sqp[ns];
            nvv[rowbase + ns] = sqrtf(sqp[ns]) + EPS;
        }
    }
}

// ---------------- Stage 2: LDS-staged slab, split-fp16 MFMA, 2-phase pipeline per b ----------------
// grid: 256 blocks (t = bid&31, rowgroup64 = bid>>5), 512 threads = 8 waves.
// wave w: rowtile rt=w>>1 (16 rows), col-half cg=w&1 (128 cols per phase, 256 total).
// LDS: zh_s 64K | zl_s 64K | norms[2][nv 2K + sq 2K] | rs[2][64] f32
#define NORMOFS 131072
#define RSOFS   139264
#define LDSSZ   139776

__global__ __launch_bounds__(512, 2) void att6_kernel(const _Float16* __restrict__ zh,
                                                      const _Float16* __restrict__ zl,
                                                      const float* __restrict__ sqv,
                                                      const float* __restrict__ nvv,
                                                      float* __restrict__ out) {
    char* lds = dynsmem;
    const int tid  = threadIdx.x;
    const int w    = tid >> 6;
    const int lane = tid & 63;
    const int l15  = lane & 15;
    const int g    = lane >> 4;
    const int rt   = w >> 1;
    const int cg   = w & 1;
    const int t    = blockIdx.x & 31;
    const int n0   = (blockIdx.x >> 5) * 64;
    const int u0   = g;        // d-octet for k-block s=0
    const int u1   = 4 + g;    // d-octet for k-block s=1

    // ---- staging helpers (wave w issues 8 x 1KB slab chunks; waves 0-3 norms) ----
    auto stage_slab = [&](int h, int bb2) {
        const size_t slabbyte = (((size_t)bb2 * TT + t) * NN) * (size_t)(DD * 2);
        #pragma unroll
        for (int i = 0; i < 8; ++i) {
            const int c = w * 8 + i;                 // 0..63
            const int within = c & 31;
            const char* gsrc = (const char*)(c < 32 ? zh : zl) + slabbyte
                             + (size_t)h * 32768 + within * 1024 + lane * 16;
            char* ldst = lds + (c < 32 ? 0 : 65536) + h * 32768 + within * 1024;
            gl_lds16(gsrc, ldst);
        }
    };
    auto stage_norms = [&](int bn) {
        const int pb = bn & 1;
        const size_t nbyte = (((size_t)bn * TT + t) * NN) * 4;
        if (w < 2) {
            gl_lds16((const char*)nvv + nbyte + w * 1024 + lane * 16,
                     lds + NORMOFS + pb * 4096 + w * 1024);
        } else if (w < 4) {
            gl_lds16((const char*)sqv + nbyte + (w - 2) * 1024 + lane * 16,
                     lds + NORMOFS + pb * 4096 + 2048 + (w - 2) * 1024);
        }
    };

    // prologue: stage half0 of b=0 + norms(b=0)
    stage_slab(0, 0);
    stage_norms(0);
    __syncthreads();

    float acc[16][4];
    #pragma unroll
    for (int ct = 0; ct < 16; ++ct)
        #pragma unroll
        for (int ri = 0; ri < 4; ++ri) acc[ct][ri] = 0.f;

    half4v atth[16];

#define COMPUTE_PHASE(H)                                                          \
    {                                                                             \
        _Pragma("unroll")                                                         \
        for (int ct = 0; ct < 8; ++ct) {                                          \
            const int cti  = (H) * 8 + ct;                                        \
            const int col  = (H) * 256 + cg * 128 + ct * 16 + l15;                \
            const int kk   = col & 7;                                             \
            const unsigned colbyte = (unsigned)col * 128;                         \
            half8 bh0 = *(const half8*)(lds + colbyte + ((u0 ^ kk) << 4));        \
            half8 bh1 = *(const half8*)(lds + colbyte + ((u1 ^ kk) << 4));        \
            half8 bl0 = *(const half8*)(lds + 65536 + colbyte + ((u0 ^ kk) << 4));\
            half8 bl1 = *(const half8*)(lds + 65536 + colbyte + ((u1 ^ kk) << 4));\
            f32x4 dhh = {0.f,0.f,0.f,0.f};                                        \
            f32x4 dhl = {0.f,0.f,0.f,0.f};                                        \
            f32x4 dlh = {0.f,0.f,0.f,0.f};                                        \
            dhh = __builtin_amdgcn_mfma_f32_16x16x32_f16(ah[0], bh0, dhh, 0,0,0); \
            dhl = __builtin_amdgcn_mfma_f32_16x16x32_f16(ah[0], bl0, dhl, 0,0,0); \
            dlh = __builtin_amdgcn_mfma_f32_16x16x32_f16(al[0], bh0, dlh, 0,0,0); \
            dhh = __builtin_amdgcn_mfma_f32_16x16x32_f16(ah[1], bh1, dhh, 0,0,0); \
            dhl = __builtin_amdgcn_mfma_f32_16x16x32_f16(ah[1], bl1, dhl, 0,0,0); \
            dlh = __builtin_amdgcn_mfma_f32_16x16x32_f16(al[1], bh1, dlh, 0,0,0); \
            f32x4 d = dhh + dhl + dlh;                                            \
            const float nm  = *(const float*)(lds + NORMOFS + pb * 4096 + col * 4);        \
            const float sqm = *(const float*)(lds + NORMOFS + pb * 4096 + 2048 + col * 4); \
            const float nmi = __builtin_amdgcn_rcpf(nm);                          \
            float pr[4], s2[4], rc[4];                                            \
            _Pragma("unroll")                                                     \
            for (int ri = 0; ri < 4; ++ri) {                                      \
                pr[ri] = nri[ri] * nmi;                                           \
                s2[ri] = sq_r[ri] + sqm;                                          \
                rc[ri] = __builtin_amdgcn_rcpf(nr[ri] + nm + EPS);                \
            }                                                                     \
            _Pragma("unroll")                                                     \
            for (int ri = 0; ri < 4; ++ri) {                                      \
                float dot = d[ri];                                                \
                float cs  = dot * pr[ri];                                         \
                float d2  = fmaxf(fmaf(dot, -2.f, s2[ri]), 0.f);                  \
                float dn  = __builtin_amdgcn_sqrtf(d2);                           \
                float a   = __expf(fmaf(dn, -rc[ri], cs));                        \
                atth[cti][ri] = (_Float16)a;                                      \
                rs[ri] += a;                                                      \
            }                                                                     \
        }                                                                         \
    }

    for (int b = 0; b < BB; ++b) {
        const int pb = b & 1;
        const size_t slabh = ((size_t)b * TT + t) * NN * DD;

        // A fragments from global (swizzled layout): rows n0 + rt*16 + l15
        const int arow = n0 + rt * 16 + l15;
        const int ak   = arow & 7;
        half8 ah[2], al[2];
        {
            const size_t ro = slabh + (size_t)arow * DD;
            ah[0] = *(const half8*)(zh + ro + ((u0 ^ ak) * 8));
            ah[1] = *(const half8*)(zh + ro + ((u1 ^ ak) * 8));
            al[0] = *(const half8*)(zl + ro + ((u0 ^ ak) * 8));
            al[1] = *(const half8*)(zl + ro + ((u1 ^ ak) * 8));
        }
        // row norms from LDS norms[pb]
        float nr[4], sq_r[4], nri[4];
        #pragma unroll
        for (int ri = 0; ri < 4; ++ri) {
            const int rrow = n0 + rt * 16 + g * 4 + ri;
            nr[ri]   = *(const float*)(lds + NORMOFS + pb * 4096 + rrow * 4);
            sq_r[ri] = *(const float*)(lds + NORMOFS + pb * 4096 + 2048 + rrow * 4);
            nri[ri]  = __builtin_amdgcn_rcpf(nr[ri]);
        }

        float rs[4] = {0.f, 0.f, 0.f, 0.f};

        stage_slab(1, b);            // issue half1 loads (hide under phase0 compute)
        COMPUTE_PHASE(0)
        __syncthreads();             // half1 staged; half0 LDS now dead

        if (b < BB - 1) {            // issue next b's half0 + norms (hide under phase1)
            stage_slab(0, b + 1);
            stage_norms(b + 1);
        }
        COMPUTE_PHASE(1)

        // row-sum: shfl over l15, then combine the 2 col-half waves via LDS
        #pragma unroll
        for (int ri = 0; ri < 4; ++ri) {
            float v = rs[ri];
            v += __shfl_xor(v, 1);
            v += __shfl_xor(v, 2);
            v += __shfl_xor(v, 4);
            v += __shfl_xor(v, 8);
            rs[ri] = v;
        }
        if (l15 == 0) {
            #pragma unroll
            for (int ri = 0; ri < 4; ++ri)
                *(float*)(lds + RSOFS + (cg * 64 + rt * 16 + g * 4 + ri) * 4) = rs[ri];
        }
        __syncthreads();             // next half0 staged; rs visible

        #pragma unroll
        for (int ri = 0; ri < 4; ++ri) {
            const int rl = rt * 16 + g * 4 + ri;
            float tot = *(const float*)(lds + RSOFS + rl * 4)
                      + *(const float*)(lds + RSOFS + 256 + rl * 4);
            float rinv = __builtin_amdgcn_rcpf(tot + EPS);
            #pragma unroll
            for (int ct = 0; ct < 16; ++ct)
                acc[ct][ri] += (float)atth[ct][ri] * rinv;
        }
    }

    // out epilogue: 4 rounds of 16-row LDS transpose (slab LDS is dead)
    for (int r = 0; r < 4; ++r) {
        if (rt == r) {
            #pragma unroll
            for (int ri = 0; ri < 4; ++ri)
                #pragma unroll
                for (int ct = 0; ct < 16; ++ct) {
                    const int col = (ct >> 3) * 256 + cg * 128 + (ct & 7) * 16 + l15;
                    *(float*)(lds + ((g * 4 + ri) * 516 + col) * 4) = acc[ct][ri] * 0.125f;
                }
        }
        __syncthreads();
        #pragma unroll
        for (int it = 0; it < 4; ++it) {
            const int idx4 = tid + it * 512;
            const int row  = idx4 >> 7;
            const int cc   = (idx4 & 127) * 4;
            float4 v = *(const float4*)(lds + (row * 516 + cc) * 4);
            *(float4*)(out + ((size_t)t * NN + n0 + r * 16 + row) * NN + cc) = v;
        }
        __syncthreads();
    }
}

extern "C" void kernel_launch(void* const* d_in, const int* in_sizes, int n_in,
                              void* d_out, int out_size, void* d_ws, size_t ws_size,
                              hipStream_t stream) {
    const float* x    = (const float*)d_in[0];
    const float* W    = (const float*)d_in[1];
    const float* bias = (const float*)d_in[2];
    float* out = (float*)d_out;

    const size_t ZELEMS = (size_t)BB * TT * NN * DD;
    _Float16* zh = (_Float16*)d_ws;
    _Float16* zl = zh + ZELEMS;
    float* sqv = (float*)(zh + 2 * ZELEMS);
    float* nvv = sqv + (size_t)BB * TT * NN;

    z_kernel<<<dim3(BB * (NN / 2)), dim3(256), 66560, stream>>>(x, W, bias, zh, zl, sqv, nvv);
    att6_kernel<<<dim3(256), dim3(512), LDSSZ, stream>>>(zh, zl, sqv, nvv, out);
}